// Round 2
// baseline (1391.977 us; speedup 1.0000x reference)
//
#include <hip/hip_runtime.h>
#include <hip/hip_cooperative_groups.h>

namespace cg = cooperative_groups;

#define W 256
#define H 256
#define HW (W*H)
#define NB 12
#define ROWS 16                 // rows per block
#define BPI (H/ROWS)            // 16 blocks per image
#define NBLK (NB*BPI)           // 192 blocks total (<= 256 CUs, 1 block/CU)
#define NTHREADS 1024
#define NUM_ITER 20
#define TVEPS 1e-8f

// d_ws halo layout: halo[parity][block][plane][W], plane:
//  0:p1x(r0) 1:p1y(r0) 2:p2x(r0) 3:p2y(r0) 4:p1y(r1) 5:p2y(r1) 6:p1y(r15) 7:p2y(r15)
#define HPLANES 8

__global__ __launch_bounds__(NTHREADS) void tvl1_coop_kernel(
    const float* __restrict__ xin,
    const float* __restrict__ lam,
    const float* __restrict__ tau,
    const float* __restrict__ theta,
    const float* __restrict__ wxv,
    const float* __restrict__ wyv,
    float* __restrict__ uout,
    float* __restrict__ halo)
{
    __shared__ float s_u0[ROWS+1][W];
    __shared__ float s_u1[ROWS+1][W];
    __shared__ float s_p1x[ROWS][W];
    __shared__ float s_p1y[ROWS][W];
    __shared__ float s_p2x[ROWS][W];
    __shared__ float s_p2y[ROWS][W];
    __shared__ float s_hx1[W];      // p1x at halo row 16 (neighbor's row 0)
    __shared__ float s_hx2[W];      // p2x at halo row 16

    const int b   = blockIdx.x;
    const int n   = b / BPI;        // image index
    const int bi  = b % BPI;        // strip index within image
    const int r0  = bi * ROWS;      // first global row of strip
    const int tid = threadIdx.x;
    const int x   = tid & (W-1);
    const int ry  = tid >> 8;       // 0..3; thread handles rows ry, ry+4, ry+8, ry+12
    const bool notTop = (bi > 0);
    const bool notBot = (bi < BPI-1);

    const float th0  = theta[0];
    const float tl   = th0 * lam[0];
    const float tt   = tau[0] / th0;
    const float wx0 = wxv[0], wx1c = wxv[1], wx2 = wxv[2];
    const float wy0 = wyv[0], wy1c = wyv[1], wy2 = wyv[2];

    const float* __restrict__ I0 = xin + (size_t)n * HW;
    const float* __restrict__ I1 = xin + (size_t)(NB + n) * HW;

    // ---- precompute rho / gx / gy for own rows (+ halo row for ry==0) ----
    float rr[5], gxr[5], gyr[5];
    auto grad_at = [&](int gy_i, float& rv, float& gxv, float& gyv) {
        const int idx = gy_i * W + x;
        const bool xm = x > 0, xp = x < W-1, ym = gy_i > 0, yp = gy_i < H-1;
        float a00=0.f,a01=0.f,a02=0.f,a10=0.f,a12=0.f,a20=0.f,a21=0.f,a22=0.f;
        if (ym) { a01 = I1[idx-W]; if (xm) a00 = I1[idx-W-1]; if (xp) a02 = I1[idx-W+1]; }
        if (xm) a10 = I1[idx-1];
        if (xp) a12 = I1[idx+1];
        if (yp) { a21 = I1[idx+W]; if (xm) a20 = I1[idx+W-1]; if (xp) a22 = I1[idx+W+1]; }
        gxv = ((a02-a00) + 2.f*(a12-a10) + (a22-a20)) * (1.f/6.f);
        gyv = ((a20-a00) + 2.f*(a21-a01) + (a22-a02)) * (1.f/6.f);
        rv  = I1[idx] - I0[idx];
    };
    #pragma unroll
    for (int r = 0; r < 4; ++r) grad_at(r0 + ry + 4*r, rr[r], gxr[r], gyr[r]);
    rr[4] = 0.f; gxr[4] = 0.f; gyr[4] = 0.f;
    if (ry == 0 && notBot) grad_at(r0 + ROWS, rr[4], gxr[4], gyr[4]);

    // ---- zero-init state in LDS ----
    {
        float* zu0 = &s_u0[0][0]; float* zu1 = &s_u1[0][0];
        for (int k = tid; k < (ROWS+1)*W; k += NTHREADS) { zu0[k] = 0.f; zu1[k] = 0.f; }
        float* z1 = &s_p1x[0][0]; float* z2 = &s_p1y[0][0];
        float* z3 = &s_p2x[0][0]; float* z4 = &s_p2y[0][0];
        for (int k = tid; k < ROWS*W; k += NTHREADS) { z1[k]=0.f; z2[k]=0.f; z3[k]=0.f; z4[k]=0.f; }
        if (tid < W) { s_hx1[tid] = 0.f; s_hx2[tid] = 0.f; }
    }
    __syncthreads();

    cg::grid_group grid = cg::this_grid();

    for (int it = 0; it < NUM_ITER; ++it) {
        // ---- read halos written last iteration (agent-scope: cross-XCD coherent) ----
        float hup1 = 0.f, hup2 = 0.f;        // p1y,p2y at row -1 (ry==0, j==0)
        float hd1y16 = 0.f, hd2y16 = 0.f;    // p1y,p2y at row 16 (ry==0: j==16; ry==3: j==15)
        float hd1y17 = 0.f, hd2y17 = 0.f;    // p1y,p2y at row 17 (ry==0: j==16)
        if (it > 0) {
            const float* hb = halo + (size_t)((it-1) & 1) * NBLK * HPLANES * W;
            if (notTop && ry == 0) {
                const float* hu = hb + (size_t)(b-1) * HPLANES * W;
                hup1 = __hip_atomic_load(hu + 6*W + x, __ATOMIC_RELAXED, __HIP_MEMORY_SCOPE_AGENT);
                hup2 = __hip_atomic_load(hu + 7*W + x, __ATOMIC_RELAXED, __HIP_MEMORY_SCOPE_AGENT);
            }
            if (notBot) {
                const float* hd = hb + (size_t)(b+1) * HPLANES * W;
                if (ry == 0 || ry == 3) {
                    hd1y16 = __hip_atomic_load(hd + 1*W + x, __ATOMIC_RELAXED, __HIP_MEMORY_SCOPE_AGENT);
                    hd2y16 = __hip_atomic_load(hd + 3*W + x, __ATOMIC_RELAXED, __HIP_MEMORY_SCOPE_AGENT);
                }
                if (ry == 0) {
                    hd1y17 = __hip_atomic_load(hd + 4*W + x, __ATOMIC_RELAXED, __HIP_MEMORY_SCOPE_AGENT);
                    hd2y17 = __hip_atomic_load(hd + 5*W + x, __ATOMIC_RELAXED, __HIP_MEMORY_SCOPE_AGENT);
                }
                if (tid < W) {
                    const float* hd2 = hb + (size_t)(b+1) * HPLANES * W;
                    s_hx1[tid] = __hip_atomic_load(hd2 + 0*W + tid, __ATOMIC_RELAXED, __HIP_MEMORY_SCOPE_AGENT);
                    s_hx2[tid] = __hip_atomic_load(hd2 + 2*W + tid, __ATOMIC_RELAXED, __HIP_MEMORY_SCOPE_AGENT);
                }
            }
            __syncthreads();
        }

        // ---- u-step: own rows ----
        #pragma unroll
        for (int r = 0; r < 4; ++r) {
            const int j = ry + 4*r;
            const float gxv = gxr[r], gyv = gyr[r], rcv = rr[r];
            const float u0 = s_u0[j][x], u1 = s_u1[j][x];
            const float rhov = rcv + gxv*u0 + gyv*u1;
            const float ng = gxv*gxv + gyv*gyv + TVEPS;
            const float th = tl * ng;
            float s0, s1;
            if (fabsf(rhov) < th) { const float d = rhov / ng; s0 = d*gxv; s1 = d*gyv; }
            else { const float sg = (rhov > 0.f) ? 1.f : ((rhov < 0.f) ? -1.f : 0.f);
                   s0 = tl*gxv*sg; s1 = tl*gyv*sg; }
            const float p1xc = s_p1x[j][x];
            const float p1xm = (x > 0)   ? s_p1x[j][x-1] : 0.f;
            const float p1xp = (x < W-1) ? s_p1x[j][x+1] : 0.f;
            const float p2xc = s_p2x[j][x];
            const float p2xm = (x > 0)   ? s_p2x[j][x-1] : 0.f;
            const float p2xp = (x < W-1) ? s_p2x[j][x+1] : 0.f;
            const float p1ym = (j > 0) ? s_p1y[j-1][x] : hup1;   // bi==0: hup1 stays 0 (pad)
            const float p2ym = (j > 0) ? s_p2y[j-1][x] : hup2;
            const float p1yc = s_p1y[j][x];
            const float p2yc = s_p2y[j][x];
            const float p1yp = (j < ROWS-1) ? s_p1y[j+1][x] : hd1y16; // bottom strip: 0 (pad)
            const float p2yp = (j < ROWS-1) ? s_p2y[j+1][x] : hd2y16;
            const float d1 = wx0*p1xm + wx1c*p1xc + wx2*p1xp + wy0*p1ym + wy1c*p1yc + wy2*p1yp;
            const float d2 = wx0*p2xm + wx1c*p2xc + wx2*p2xp + wy0*p2ym + wy1c*p2yc + wy2*p2yp;
            s_u0[j][x] = (u0 - s0) + th0*d1;
            s_u1[j][x] = (u1 - s1) + th0*d2;
        }
        // ---- u-step: halo row 16 (bitwise-identical to neighbor's row 0) ----
        if (ry == 0 && notBot && it < NUM_ITER-1) {
            const int j = ROWS;
            const float gxv = gxr[4], gyv = gyr[4], rcv = rr[4];
            const float u0 = s_u0[j][x], u1 = s_u1[j][x];
            const float rhov = rcv + gxv*u0 + gyv*u1;
            const float ng = gxv*gxv + gyv*gyv + TVEPS;
            const float th = tl * ng;
            float s0, s1;
            if (fabsf(rhov) < th) { const float d = rhov / ng; s0 = d*gxv; s1 = d*gyv; }
            else { const float sg = (rhov > 0.f) ? 1.f : ((rhov < 0.f) ? -1.f : 0.f);
                   s0 = tl*gxv*sg; s1 = tl*gyv*sg; }
            const float p1xc = s_hx1[x];
            const float p1xm = (x > 0)   ? s_hx1[x-1] : 0.f;
            const float p1xp = (x < W-1) ? s_hx1[x+1] : 0.f;
            const float p2xc = s_hx2[x];
            const float p2xm = (x > 0)   ? s_hx2[x-1] : 0.f;
            const float p2xp = (x < W-1) ? s_hx2[x+1] : 0.f;
            const float p1ym = s_p1y[ROWS-1][x];
            const float p2ym = s_p2y[ROWS-1][x];
            const float p1yc = hd1y16, p2yc = hd2y16;
            const float p1yp = hd1y17, p2yp = hd2y17;
            const float d1 = wx0*p1xm + wx1c*p1xc + wx2*p1xp + wy0*p1ym + wy1c*p1yc + wy2*p1yp;
            const float d2 = wx0*p2xm + wx1c*p2xc + wx2*p2xp + wy0*p2ym + wy1c*p2yc + wy2*p2yp;
            s_u0[j][x] = (u0 - s0) + th0*d1;
            s_u1[j][x] = (u1 - s1) + th0*d2;
        }
        __syncthreads();

        if (it == NUM_ITER-1) {
            // final: write u (after 20th u-step; p-step of last body doesn't affect u)
            float* __restrict__ o0 = uout + (size_t)(2*n)   * HW;
            float* __restrict__ o1 = uout + (size_t)(2*n+1) * HW;
            #pragma unroll
            for (int r = 0; r < 4; ++r) {
                const int j = ry + 4*r;
                const int idx = (r0 + j) * W + x;
                o0[idx] = s_u0[j][x];
                o1[idx] = s_u1[j][x];
            }
        } else {
            // ---- p-step: own rows (uses new u incl. halo row) ----
            #pragma unroll
            for (int r = 0; r < 4; ++r) {
                const int j = ry + 4*r;
                const int gy_i = r0 + j;
                const float c0 = s_u0[j][x], c1 = s_u1[j][x];
                const float u0xp = (x < W-1) ? s_u0[j][x+1] : 0.f;
                const float u1xp = (x < W-1) ? s_u1[j][x+1] : 0.f;
                const bool ypad = (gy_i == H-1);
                const float u0yp = ypad ? 0.f : s_u0[j+1][x];  // j==15 & !bottom: halo u row
                const float u1yp = ypad ? 0.f : s_u1[j+1][x];
                const float g1x = u0xp - c0;
                const float g1y = u0yp - c0;
                const float g2x = u1xp - c1;
                const float g2y = u1yp - c1;
                const float den1 = 1.f + tt * (fabsf(g1x) + fabsf(g1y));
                const float den2 = 1.f + tt * (fabsf(g2x) + fabsf(g2y));
                s_p1x[j][x] = (s_p1x[j][x] + tt*g1x) / den1;
                s_p1y[j][x] = (s_p1y[j][x] + tt*g1y) / den1;
                s_p2x[j][x] = (s_p2x[j][x] + tt*g2x) / den2;
                s_p2y[j][x] = (s_p2y[j][x] + tt*g2y) / den2;
            }
            __syncthreads();

            // ---- publish halos for next iteration (ping-pong by parity) ----
            float* hwp = halo + ((size_t)(it & 1) * NBLK + b) * HPLANES * W;
            for (int k = tid; k < HPLANES*W; k += NTHREADS) {
                const int pl = k >> 8, xc = k & (W-1);
                float v;
                if      (pl == 0) v = s_p1x[0][xc];
                else if (pl == 1) v = s_p1y[0][xc];
                else if (pl == 2) v = s_p2x[0][xc];
                else if (pl == 3) v = s_p2y[0][xc];
                else if (pl == 4) v = s_p1y[1][xc];
                else if (pl == 5) v = s_p2y[1][xc];
                else if (pl == 6) v = s_p1y[ROWS-1][xc];
                else              v = s_p2y[ROWS-1][xc];
                __hip_atomic_store(hwp + k, v, __ATOMIC_RELAXED, __HIP_MEMORY_SCOPE_AGENT);
            }
            __threadfence();
            grid.sync();
        }
    }
}

extern "C" void kernel_launch(void* const* d_in, const int* in_sizes, int n_in,
                              void* d_out, int out_size, void* d_ws, size_t ws_size,
                              hipStream_t stream) {
    const float* x     = (const float*)d_in[0];
    const float* lam   = (const float*)d_in[1];
    const float* tau   = (const float*)d_in[2];
    const float* theta = (const float*)d_in[3];
    const float* wxv   = (const float*)d_in[4];
    const float* wyv   = (const float*)d_in[5];
    float* u    = (float*)d_out;
    float* halo = (float*)d_ws;

    void* args[] = { (void*)&x, (void*)&lam, (void*)&tau, (void*)&theta,
                     (void*)&wxv, (void*)&wyv, (void*)&u, (void*)&halo };
    hipLaunchCooperativeKernel((void*)tvl1_coop_kernel, dim3(NBLK), dim3(NTHREADS),
                               args, 0, stream);
}

// Round 3
// 168.395 us; speedup vs baseline: 8.2661x; 8.2661x over previous
//
#include <hip/hip_runtime.h>

#define W 256
#define H 256
#define HW (W*H)
#define NB 12
#define ROWS 16                 // rows per block
#define BPI (H/ROWS)            // 16 blocks per image
#define NBLK (NB*BPI)           // 192 blocks (1 per CU, all co-resident)
#define NTHREADS 1024
#define NUM_ITER 20
#define TVEPS 1e-8f
#define HPLANES 8
#define FLAG_MAGIC 0x5A170000

// persistent-path d_ws layout:
//   halo : [NUM_ITER-1][NBLK][HPLANES][W] floats (write-once per call per slot)
//   flags: [NUM_ITER-1][NBLK] ints
// planes: 0:p1x(r0) 1:p1y(r0) 2:p2x(r0) 3:p2y(r0) 4:p1y(r1) 5:p2y(r1) 6:p1y(r15) 7:p2y(r15)

__global__ __launch_bounds__(NTHREADS) void tvl1_flag_kernel(
    const float* __restrict__ xin,
    const float* __restrict__ lam,
    const float* __restrict__ tau,
    const float* __restrict__ theta,
    const float* __restrict__ wxv,
    const float* __restrict__ wyv,
    float* __restrict__ uout,
    float* __restrict__ halo,
    int* __restrict__ flags)
{
    __shared__ float s_u0[ROWS+1][W];
    __shared__ float s_u1[ROWS+1][W];
    __shared__ float s_p1x[ROWS][W];
    __shared__ float s_p1y[ROWS][W];
    __shared__ float s_p2x[ROWS][W];
    __shared__ float s_p2y[ROWS][W];
    __shared__ float s_hx1[W];      // p1x at halo row 16 (neighbor's row 0)
    __shared__ float s_hx2[W];      // p2x at halo row 16

    const int b   = blockIdx.x;
    const int n   = b / BPI;
    const int bi  = b % BPI;
    const int r0  = bi * ROWS;
    const int tid = threadIdx.x;
    const int x   = tid & (W-1);
    const int ry  = tid >> 8;       // 0..3
    const bool notTop = (bi > 0);
    const bool notBot = (bi < BPI-1);

    const float th0  = theta[0];
    const float tl   = th0 * lam[0];
    const float tt   = tau[0] / th0;
    const float wx0 = wxv[0], wx1c = wxv[1], wx2 = wxv[2];
    const float wy0 = wyv[0], wy1c = wyv[1], wy2 = wyv[2];

    const float* __restrict__ I0 = xin + (size_t)n * HW;
    const float* __restrict__ I1 = xin + (size_t)(NB + n) * HW;

    float rr[5], gxr[5], gyr[5];
    auto grad_at = [&](int gy_i, float& rv, float& gxv, float& gyv) {
        const int idx = gy_i * W + x;
        const bool xm = x > 0, xp = x < W-1, ym = gy_i > 0, yp = gy_i < H-1;
        float a00=0.f,a01=0.f,a02=0.f,a10=0.f,a12=0.f,a20=0.f,a21=0.f,a22=0.f;
        if (ym) { a01 = I1[idx-W]; if (xm) a00 = I1[idx-W-1]; if (xp) a02 = I1[idx-W+1]; }
        if (xm) a10 = I1[idx-1];
        if (xp) a12 = I1[idx+1];
        if (yp) { a21 = I1[idx+W]; if (xm) a20 = I1[idx+W-1]; if (xp) a22 = I1[idx+W+1]; }
        gxv = ((a02-a00) + 2.f*(a12-a10) + (a22-a20)) * (1.f/6.f);
        gyv = ((a20-a00) + 2.f*(a21-a01) + (a22-a02)) * (1.f/6.f);
        rv  = I1[idx] - I0[idx];
    };
    #pragma unroll
    for (int r = 0; r < 4; ++r) grad_at(r0 + ry + 4*r, rr[r], gxr[r], gyr[r]);
    rr[4] = 0.f; gxr[4] = 0.f; gyr[4] = 0.f;
    if (ry == 0 && notBot) grad_at(r0 + ROWS, rr[4], gxr[4], gyr[4]);

    {
        float* zu0 = &s_u0[0][0]; float* zu1 = &s_u1[0][0];
        for (int k = tid; k < (ROWS+1)*W; k += NTHREADS) { zu0[k] = 0.f; zu1[k] = 0.f; }
        float* z1 = &s_p1x[0][0]; float* z2 = &s_p1y[0][0];
        float* z3 = &s_p2x[0][0]; float* z4 = &s_p2y[0][0];
        for (int k = tid; k < ROWS*W; k += NTHREADS) { z1[k]=0.f; z2[k]=0.f; z3[k]=0.f; z4[k]=0.f; }
        if (tid < W) { s_hx1[tid] = 0.f; s_hx2[tid] = 0.f; }
    }
    __syncthreads();

    for (int it = 0; it < NUM_ITER; ++it) {
        float hup1 = 0.f, hup2 = 0.f;
        float hd1y16 = 0.f, hd2y16 = 0.f;
        float hd1y17 = 0.f, hd2y17 = 0.f;
        if (it > 0) {
            // wait for neighbors' iteration it-1 publish (release/acquire, agent scope)
            if (tid < 2) {
                const bool need = (tid == 0) ? notBot : notTop;
                if (need) {
                    const int src = (tid == 0) ? (b + 1) : (b - 1);
                    const int tgt = FLAG_MAGIC | (it - 1);
                    while (__hip_atomic_load(&flags[(it-1)*NBLK + src],
                                             __ATOMIC_ACQUIRE, __HIP_MEMORY_SCOPE_AGENT) != tgt) {
                        __builtin_amdgcn_s_sleep(2);
                    }
                }
            }
            __syncthreads();

            const float* hb = halo + (size_t)(it-1) * NBLK * HPLANES * W;
            if (notTop && ry == 0) {
                const float* hu = hb + (size_t)(b-1) * HPLANES * W;
                hup1 = __hip_atomic_load(hu + 6*W + x, __ATOMIC_RELAXED, __HIP_MEMORY_SCOPE_AGENT);
                hup2 = __hip_atomic_load(hu + 7*W + x, __ATOMIC_RELAXED, __HIP_MEMORY_SCOPE_AGENT);
            }
            if (notBot) {
                const float* hd = hb + (size_t)(b+1) * HPLANES * W;
                if (ry == 0 || ry == 3) {
                    hd1y16 = __hip_atomic_load(hd + 1*W + x, __ATOMIC_RELAXED, __HIP_MEMORY_SCOPE_AGENT);
                    hd2y16 = __hip_atomic_load(hd + 3*W + x, __ATOMIC_RELAXED, __HIP_MEMORY_SCOPE_AGENT);
                }
                if (ry == 0) {
                    hd1y17 = __hip_atomic_load(hd + 4*W + x, __ATOMIC_RELAXED, __HIP_MEMORY_SCOPE_AGENT);
                    hd2y17 = __hip_atomic_load(hd + 5*W + x, __ATOMIC_RELAXED, __HIP_MEMORY_SCOPE_AGENT);
                }
                if (tid < W) {
                    s_hx1[tid] = __hip_atomic_load(hd + 0*W + tid, __ATOMIC_RELAXED, __HIP_MEMORY_SCOPE_AGENT);
                    s_hx2[tid] = __hip_atomic_load(hd + 2*W + tid, __ATOMIC_RELAXED, __HIP_MEMORY_SCOPE_AGENT);
                }
            }
            __syncthreads();
        }

        // ---- u-step: own rows ----
        #pragma unroll
        for (int r = 0; r < 4; ++r) {
            const int j = ry + 4*r;
            const float gxv = gxr[r], gyv = gyr[r], rcv = rr[r];
            const float u0 = s_u0[j][x], u1 = s_u1[j][x];
            const float rhov = rcv + gxv*u0 + gyv*u1;
            const float ng = gxv*gxv + gyv*gyv + TVEPS;
            const float th = tl * ng;
            float s0, s1;
            if (fabsf(rhov) < th) { const float d = rhov / ng; s0 = d*gxv; s1 = d*gyv; }
            else { const float sg = (rhov > 0.f) ? 1.f : ((rhov < 0.f) ? -1.f : 0.f);
                   s0 = tl*gxv*sg; s1 = tl*gyv*sg; }
            const float p1xc = s_p1x[j][x];
            const float p1xm = (x > 0)   ? s_p1x[j][x-1] : 0.f;
            const float p1xp = (x < W-1) ? s_p1x[j][x+1] : 0.f;
            const float p2xc = s_p2x[j][x];
            const float p2xm = (x > 0)   ? s_p2x[j][x-1] : 0.f;
            const float p2xp = (x < W-1) ? s_p2x[j][x+1] : 0.f;
            const float p1ym = (j > 0) ? s_p1y[j-1][x] : hup1;
            const float p2ym = (j > 0) ? s_p2y[j-1][x] : hup2;
            const float p1yc = s_p1y[j][x];
            const float p2yc = s_p2y[j][x];
            const float p1yp = (j < ROWS-1) ? s_p1y[j+1][x] : hd1y16;
            const float p2yp = (j < ROWS-1) ? s_p2y[j+1][x] : hd2y16;
            const float d1 = wx0*p1xm + wx1c*p1xc + wx2*p1xp + wy0*p1ym + wy1c*p1yc + wy2*p1yp;
            const float d2 = wx0*p2xm + wx1c*p2xc + wx2*p2xp + wy0*p2ym + wy1c*p2yc + wy2*p2yp;
            s_u0[j][x] = (u0 - s0) + th0*d1;
            s_u1[j][x] = (u1 - s1) + th0*d2;
        }
        // ---- u-step: halo row 16 (bitwise-identical to neighbor's row 0) ----
        if (ry == 0 && notBot && it < NUM_ITER-1) {
            const int j = ROWS;
            const float gxv = gxr[4], gyv = gyr[4], rcv = rr[4];
            const float u0 = s_u0[j][x], u1 = s_u1[j][x];
            const float rhov = rcv + gxv*u0 + gyv*u1;
            const float ng = gxv*gxv + gyv*gyv + TVEPS;
            const float th = tl * ng;
            float s0, s1;
            if (fabsf(rhov) < th) { const float d = rhov / ng; s0 = d*gxv; s1 = d*gyv; }
            else { const float sg = (rhov > 0.f) ? 1.f : ((rhov < 0.f) ? -1.f : 0.f);
                   s0 = tl*gxv*sg; s1 = tl*gyv*sg; }
            const float p1xc = s_hx1[x];
            const float p1xm = (x > 0)   ? s_hx1[x-1] : 0.f;
            const float p1xp = (x < W-1) ? s_hx1[x+1] : 0.f;
            const float p2xc = s_hx2[x];
            const float p2xm = (x > 0)   ? s_hx2[x-1] : 0.f;
            const float p2xp = (x < W-1) ? s_hx2[x+1] : 0.f;
            const float p1ym = s_p1y[ROWS-1][x];
            const float p2ym = s_p2y[ROWS-1][x];
            const float p1yc = hd1y16, p2yc = hd2y16;
            const float p1yp = hd1y17, p2yp = hd2y17;
            const float d1 = wx0*p1xm + wx1c*p1xc + wx2*p1xp + wy0*p1ym + wy1c*p1yc + wy2*p1yp;
            const float d2 = wx0*p2xm + wx1c*p2xc + wx2*p2xp + wy0*p2ym + wy1c*p2yc + wy2*p2yp;
            s_u0[j][x] = (u0 - s0) + th0*d1;
            s_u1[j][x] = (u1 - s1) + th0*d2;
        }
        __syncthreads();

        if (it == NUM_ITER-1) {
            float* __restrict__ o0 = uout + (size_t)(2*n)   * HW;
            float* __restrict__ o1 = uout + (size_t)(2*n+1) * HW;
            #pragma unroll
            for (int r = 0; r < 4; ++r) {
                const int j = ry + 4*r;
                const int idx = (r0 + j) * W + x;
                o0[idx] = s_u0[j][x];
                o1[idx] = s_u1[j][x];
            }
        } else {
            // ---- p-step ----
            #pragma unroll
            for (int r = 0; r < 4; ++r) {
                const int j = ry + 4*r;
                const int gy_i = r0 + j;
                const float c0 = s_u0[j][x], c1 = s_u1[j][x];
                const float u0xp = (x < W-1) ? s_u0[j][x+1] : 0.f;
                const float u1xp = (x < W-1) ? s_u1[j][x+1] : 0.f;
                const bool ypad = (gy_i == H-1);
                const float u0yp = ypad ? 0.f : s_u0[j+1][x];
                const float u1yp = ypad ? 0.f : s_u1[j+1][x];
                const float g1x = u0xp - c0;
                const float g1y = u0yp - c0;
                const float g2x = u1xp - c1;
                const float g2y = u1yp - c1;
                const float den1 = 1.f + tt * (fabsf(g1x) + fabsf(g1y));
                const float den2 = 1.f + tt * (fabsf(g2x) + fabsf(g2y));
                s_p1x[j][x] = (s_p1x[j][x] + tt*g1x) / den1;
                s_p1y[j][x] = (s_p1y[j][x] + tt*g1y) / den1;
                s_p2x[j][x] = (s_p2x[j][x] + tt*g2x) / den2;
                s_p2y[j][x] = (s_p2y[j][x] + tt*g2y) / den2;
            }
            __syncthreads();

            // ---- publish halos for iteration it (write-once slot) ----
            float* hwp = halo + ((size_t)it * NBLK + b) * HPLANES * W;
            for (int k = tid; k < HPLANES*W; k += NTHREADS) {
                const int pl = k >> 8, xc = k & (W-1);
                float v;
                if      (pl == 0) v = s_p1x[0][xc];
                else if (pl == 1) v = s_p1y[0][xc];
                else if (pl == 2) v = s_p2x[0][xc];
                else if (pl == 3) v = s_p2y[0][xc];
                else if (pl == 4) v = s_p1y[1][xc];
                else if (pl == 5) v = s_p2y[1][xc];
                else if (pl == 6) v = s_p1y[ROWS-1][xc];
                else              v = s_p2y[ROWS-1][xc];
                __hip_atomic_store(hwp + k, v, __ATOMIC_RELAXED, __HIP_MEMORY_SCOPE_AGENT);
            }
            __syncthreads();
            if (tid == 0) {
                __hip_atomic_store(&flags[it*NBLK + b], FLAG_MAGIC | it,
                                   __ATOMIC_RELEASE, __HIP_MEMORY_SCOPE_AGENT);
            }
        }
    }
}

// ---------------- fallback path (round-1, known good) ----------------

__global__ void precompute_kernel(const float* __restrict__ x,
                                  float* __restrict__ u,
                                  float* __restrict__ ws) {
    const int row = blockIdx.x;
    const int n = row / H, y = row % H;
    const int xx = threadIdx.x;
    const int idx = y * W + xx;
    const float* __restrict__ I0 = x + (size_t)n * HW;
    const float* __restrict__ I1 = x + (size_t)(NB + n) * HW;
    float* __restrict__ p1  = ws;
    float* __restrict__ p2  = ws + (size_t)2 * NB * HW;
    float* __restrict__ rho = ws + (size_t)4 * NB * HW;
    float* __restrict__ gxp = ws + (size_t)5 * NB * HW;
    float* __restrict__ gyp = ws + (size_t)6 * NB * HW;
    const float i1c = I1[idx];
    const bool xm = xx > 0, xp = xx < W - 1, ym = y > 0, yp = y < H - 1;
    float a00=0.f,a01=0.f,a02=0.f,a10=0.f,a12=0.f,a20=0.f,a21=0.f,a22=0.f;
    if (ym) { a01 = I1[idx-W]; if (xm) a00 = I1[idx-W-1]; if (xp) a02 = I1[idx-W+1]; }
    if (xm) a10 = I1[idx-1];
    if (xp) a12 = I1[idx+1];
    if (yp) { a21 = I1[idx+W]; if (xm) a20 = I1[idx+W-1]; if (xp) a22 = I1[idx+W+1]; }
    const float gxv = ((a02-a00) + 2.f*(a12-a10) + (a22-a20)) * (1.f/6.f);
    const float gyv = ((a20-a00) + 2.f*(a21-a01) + (a22-a02)) * (1.f/6.f);
    const size_t np = (size_t)n * HW;
    rho[np+idx] = i1c - I0[idx];
    gxp[np+idx] = gxv;
    gyp[np+idx] = gyv;
    u[(size_t)(2*n)*HW + idx] = 0.f;   u[(size_t)(2*n+1)*HW + idx] = 0.f;
    p1[(size_t)(2*n)*HW + idx] = 0.f;  p1[(size_t)(2*n+1)*HW + idx] = 0.f;
    p2[(size_t)(2*n)*HW + idx] = 0.f;  p2[(size_t)(2*n+1)*HW + idx] = 0.f;
}

__global__ void u_kernel(const float* __restrict__ ws,
                         float* __restrict__ u,
                         const float* __restrict__ lam,
                         const float* __restrict__ theta,
                         const float* __restrict__ wxv,
                         const float* __restrict__ wyv) {
    const int row = blockIdx.x;
    const int n = row / H, y = row % H;
    const int xx = threadIdx.x;
    const int idx = y * W + xx;
    const size_t np = (size_t)n * HW;
    const float* __restrict__ p1  = ws;
    const float* __restrict__ p2  = ws + (size_t)2 * NB * HW;
    const float* __restrict__ rho_c = ws + (size_t)4 * NB * HW;
    const float* __restrict__ gxp = ws + (size_t)5 * NB * HW;
    const float* __restrict__ gyp = ws + (size_t)6 * NB * HW;
    const float th0 = theta[0];
    const float tl = th0 * lam[0];
    const float wx0 = wxv[0], wx1 = wxv[1], wx2 = wxv[2];
    const float wy0 = wyv[0], wy1 = wyv[1], wy2 = wyv[2];
    const float gx = gxp[np+idx];
    const float gy = gyp[np+idx];
    float* __restrict__ u0p = u + (size_t)(2*n)*HW;
    float* __restrict__ u1p = u + (size_t)(2*n+1)*HW;
    const float u0 = u0p[idx], u1 = u1p[idx];
    const float rho = rho_c[np+idx] + gx*u0 + gy*u1;
    const float ng = gx*gx + gy*gy + TVEPS;
    const float th = tl * ng;
    float s0, s1;
    if (fabsf(rho) < th) { const float d = rho/ng; s0 = d*gx; s1 = d*gy; }
    else { const float sg = (rho > 0.f) ? 1.f : ((rho < 0.f) ? -1.f : 0.f);
           s0 = tl*gx*sg; s1 = tl*gy*sg; }
    const float v0 = u0 - s0, v1 = u1 - s1;
    const float* __restrict__ p1x = p1 + (size_t)(2*n)*HW;
    const float* __restrict__ p1y = p1 + (size_t)(2*n+1)*HW;
    const float* __restrict__ p2x = p2 + (size_t)(2*n)*HW;
    const float* __restrict__ p2y = p2 + (size_t)(2*n+1)*HW;
    float d1 = wx1*p1x[idx] + wy1*p1y[idx];
    float d2 = wx1*p2x[idx] + wy1*p2y[idx];
    if (xx > 0)     { d1 += wx0*p1x[idx-1]; d2 += wx0*p2x[idx-1]; }
    if (xx < W-1)   { d1 += wx2*p1x[idx+1]; d2 += wx2*p2x[idx+1]; }
    if (y > 0)      { d1 += wy0*p1y[idx-W]; d2 += wy0*p2y[idx-W]; }
    if (y < H-1)    { d1 += wy2*p1y[idx+W]; d2 += wy2*p2y[idx+W]; }
    u0p[idx] = v0 + th0*d1;
    u1p[idx] = v1 + th0*d2;
}

__global__ void p_kernel(const float* __restrict__ u,
                         float* __restrict__ ws,
                         const float* __restrict__ tau,
                         const float* __restrict__ theta) {
    const int row = blockIdx.x;
    const int n = row / H, y = row % H;
    const int xx = threadIdx.x;
    const int idx = y * W + xx;
    float* __restrict__ p1 = ws;
    float* __restrict__ p2 = ws + (size_t)2 * NB * HW;
    const float tt = tau[0] / theta[0];
    const float* __restrict__ u0p = u + (size_t)(2*n)*HW;
    const float* __restrict__ u1p = u + (size_t)(2*n+1)*HW;
    const float c0 = u0p[idx];
    const float g1x = ((xx < W-1) ? u0p[idx+1] : 0.f) - c0;
    const float g1y = ((y < H-1) ? u0p[idx+W] : 0.f) - c0;
    const float c1 = u1p[idx];
    const float g2x = ((xx < W-1) ? u1p[idx+1] : 0.f) - c1;
    const float g2y = ((y < H-1) ? u1p[idx+W] : 0.f) - c1;
    float* __restrict__ p1x = p1 + (size_t)(2*n)*HW;
    float* __restrict__ p1y = p1 + (size_t)(2*n+1)*HW;
    float* __restrict__ p2x = p2 + (size_t)(2*n)*HW;
    float* __restrict__ p2y = p2 + (size_t)(2*n+1)*HW;
    const float den1 = 1.f + tt * (fabsf(g1x) + fabsf(g1y));
    p1x[idx] = (p1x[idx] + tt*g1x) / den1;
    p1y[idx] = (p1y[idx] + tt*g1y) / den1;
    const float den2 = 1.f + tt * (fabsf(g2x) + fabsf(g2y));
    p2x[idx] = (p2x[idx] + tt*g2x) / den2;
    p2y[idx] = (p2y[idx] + tt*g2y) / den2;
}

extern "C" void kernel_launch(void* const* d_in, const int* in_sizes, int n_in,
                              void* d_out, int out_size, void* d_ws, size_t ws_size,
                              hipStream_t stream) {
    const float* x     = (const float*)d_in[0];
    const float* lam   = (const float*)d_in[1];
    const float* tau   = (const float*)d_in[2];
    const float* theta = (const float*)d_in[3];
    const float* wxv   = (const float*)d_in[4];
    const float* wyv   = (const float*)d_in[5];
    float* u = (float*)d_out;

    const size_t halo_floats = (size_t)(NUM_ITER-1) * NBLK * HPLANES * W;
    const size_t need = halo_floats * sizeof(float) + (size_t)(NUM_ITER-1) * NBLK * sizeof(int);

    if (ws_size >= need) {
        float* halo = (float*)d_ws;
        int* flags = (int*)((char*)d_ws + halo_floats * sizeof(float));
        void* args[] = { (void*)&x, (void*)&lam, (void*)&tau, (void*)&theta,
                         (void*)&wxv, (void*)&wyv, (void*)&u, (void*)&halo, (void*)&flags };
        hipLaunchCooperativeKernel((void*)tvl1_flag_kernel, dim3(NBLK), dim3(NTHREADS),
                                   args, 0, stream);
    } else {
        float* ws = (float*)d_ws;
        const dim3 grid(NB * H);
        const dim3 block(W);
        precompute_kernel<<<grid, block, 0, stream>>>(x, u, ws);
        for (int it = 0; it < NUM_ITER; ++it) {
            u_kernel<<<grid, block, 0, stream>>>(ws, u, lam, theta, wxv, wyv);
            p_kernel<<<grid, block, 0, stream>>>(u, ws, tau, theta);
        }
    }
}